// Round 1
// baseline (811.695 us; speedup 1.0000x reference)
//
#include <hip/hip_runtime.h>
#include <hip/hip_bf16.h>
#include <cstdint>
#include <cstddef>

#define TOK 8192
#define HID 1024
#define NE 8

typedef __bf16 bf16x4 __attribute__((ext_vector_type(4)));
typedef __bf16 bf16x8 __attribute__((ext_vector_type(8)));
typedef float floatx4 __attribute__((ext_vector_type(4)));

static __device__ __forceinline__ __bf16 f2bf(float x) {
    unsigned u = __builtin_bit_cast(unsigned, x);
    u += 0x7fffu + ((u >> 16) & 1u);   // RNE to bf16 (inputs are finite)
    unsigned short hs = (unsigned short)(u >> 16);
    return __builtin_bit_cast(__bf16, hs);
}

__global__ void zero_counts_kernel(int* counts) {
    if (threadIdx.x < NE) counts[threadIdx.x] = 0;
}

// Routing: softmax over 8 logits, top-1 expert, p = max prob.
// Bucket tokens per expert via atomics (order within expert is arbitrary — fine).
__global__ void route_kernel(const float* __restrict__ gate, float* __restrict__ scale,
                             int* __restrict__ counts, int* __restrict__ list) {
    int t = blockIdx.x * blockDim.x + threadIdx.x;
    if (t >= TOK) return;
    float g[NE];
#pragma unroll
    for (int j = 0; j < NE; j++) g[j] = gate[t * NE + j];
    float gm = g[0]; int best = 0;
#pragma unroll
    for (int j = 1; j < NE; j++) {        // strict > keeps first max (jnp.argmax semantics)
        if (g[j] > gm) { gm = g[j]; best = j; }
    }
    float s = 0.f;
#pragma unroll
    for (int j = 0; j < NE; j++) s += __expf(g[j] - gm);
    scale[t] = 1.0f / s;                  // top_p = exp(gmax)/sum = 1/sum(exp(g-gmax))
    int pos = atomicAdd(&counts[best], 1);
    list[best * TOK + pos] = t;
}

// Grouped GEMM: per block = (expert e, m-tile of 128 routed tokens, n-tile of 128 cols).
// LDS layout: stride-64 rows with XOR chunk swizzle — element k of row r lives in
// 16B-chunk position ((k>>3) ^ (r&7)). Both the transpose-stage writes (b128 along k)
// and the MFMA fragment reads (b128, 8 contiguous k) hit minimum bank aliasing.
__launch_bounds__(256)
__global__ void moe_gemm_kernel(const float* __restrict__ X, const float* __restrict__ W,
                                const float* __restrict__ Bias, const float* __restrict__ scale,
                                const int* __restrict__ counts, const int* __restrict__ list,
                                float* __restrict__ out) {
    const int bid = blockIdx.x;
    const int e  = bid >> 9;          // 512 blocks per expert
    const int nt = (bid >> 6) & 7;    // 8 n-tiles
    const int mt = bid & 63;          // 64 max m-tiles

    const int cnt = counts[e];
    if (mt * 128 >= cnt) return;
    const int mvalid = min(128, cnt - mt * 128);
    const int n0 = nt * 128;

    __shared__ __bf16 As[128 * 64];
    __shared__ __bf16 Bs[128 * 64];
    __shared__ int   tok[128];
    __shared__ float scl[128];

    const int tid = threadIdx.x;
    if (tid < 128) {
        int g = mt * 128 + tid;
        int tk = (g < cnt) ? list[e * TOK + g] : 0;
        tok[tid] = tk;
        scl[tid] = (g < cnt) ? scale[tk] : 0.f;
    }
    __syncthreads();

    // A-staging assignment: linear = tid + 256*i -> row m = linear>>4, float4-col c4 = linear&15.
    const int c4 = tid & 15;
    const float* rp[8];
    bool rv[8];
#pragma unroll
    for (int i = 0; i < 8; i++) {
        int m = (tid >> 4) + 16 * i;
        rv[i] = (m < mvalid);
        rp[i] = X + (size_t)tok[m] * HID;
    }

    // B-staging assignment: n4 = tid&31 (float4 col group), kb = tid>>5 (8-row k block).
    const int n4 = tid & 31;
    const int kb = tid >> 5;
    const float* wbase = W + (size_t)e * HID * HID + (size_t)(kb * 8) * HID + n0 + n4 * 4;

    const int lane = tid & 63;
    const int ln = lane & 15;
    const int q  = lane >> 4;
    const int wave = tid >> 6;
    const int wm = (wave >> 1) * 64;
    const int wn = (wave & 1) * 64;

    floatx4 acc[4][4];
#pragma unroll
    for (int mi = 0; mi < 4; mi++)
#pragma unroll
        for (int ni = 0; ni < 4; ni++) acc[mi][ni] = (floatx4){0.f, 0.f, 0.f, 0.f};

    for (int k0 = 0; k0 < HID; k0 += 64) {
        // ---- stage A: 128m x 64k, gathered rows, fp32 -> bf16 ----
#pragma unroll
        for (int i = 0; i < 8; i++) {
            int m = (tid >> 4) + 16 * i;
            float4 v = make_float4(0.f, 0.f, 0.f, 0.f);
            if (rv[i]) v = *(const float4*)(rp[i] + k0 + c4 * 4);
            bf16x4 b4;
            b4[0] = f2bf(v.x); b4[1] = f2bf(v.y); b4[2] = f2bf(v.z); b4[3] = f2bf(v.w);
            int chunk = c4 >> 1;
            int addr = m * 64 + ((chunk ^ (m & 7)) * 8) + (c4 & 1) * 4;
            *(bf16x4*)(&As[addr]) = b4;
        }
        // ---- stage B: 64k x 128n slice of W[e], transpose to [n][k] in registers ----
        {
            const float* wp = wbase + (size_t)k0 * HID;
            float4 rr[8];
#pragma unroll
            for (int r = 0; r < 8; r++) rr[r] = *(const float4*)(wp + (size_t)r * HID);
            __bf16 vals[8][4];
#pragma unroll
            for (int r = 0; r < 8; r++) {
                vals[r][0] = f2bf(rr[r].x); vals[r][1] = f2bf(rr[r].y);
                vals[r][2] = f2bf(rr[r].z); vals[r][3] = f2bf(rr[r].w);
            }
#pragma unroll
            for (int s = 0; s < 4; s++) {
                int j = (s + n4) & 3;           // rotate j across lanes -> spread n&7 over banks
                int n = n4 * 4 + j;
                int c = kb ^ (n & 7);
                bf16x8 pk;
#pragma unroll
                for (int r = 0; r < 8; r++) pk[r] = vals[r][j];
                *(bf16x8*)(&Bs[n * 64 + c * 8]) = pk;
            }
        }
        __syncthreads();

        // ---- compute: 2 MFMA k-chunks of 32 ----
#pragma unroll
        for (int kk = 0; kk < 64; kk += 32) {
            const int cbase = (kk >> 3) + q;    // element chunk index, 0..7
            bf16x8 af[4], bfv[4];
#pragma unroll
            for (int mi = 0; mi < 4; mi++) {
                int row = wm + mi * 16 + ln;
                af[mi] = *(const bf16x8*)(&As[row * 64 + ((cbase ^ (row & 7)) * 8)]);
            }
#pragma unroll
            for (int ni = 0; ni < 4; ni++) {
                int n = wn + ni * 16 + ln;
                bfv[ni] = *(const bf16x8*)(&Bs[n * 64 + ((cbase ^ (n & 7)) * 8)]);
            }
#pragma unroll
            for (int mi = 0; mi < 4; mi++)
#pragma unroll
                for (int ni = 0; ni < 4; ni++)
                    acc[mi][ni] = __builtin_amdgcn_mfma_f32_16x16x32_bf16(
                        af[mi], bfv[ni], acc[mi][ni], 0, 0, 0);
        }
        __syncthreads();
    }

    // ---- epilogue: out[t, n] = p_t * (acc + bias[e, n]) ----
    float bn[4];
#pragma unroll
    for (int ni = 0; ni < 4; ni++) bn[ni] = Bias[e * HID + n0 + wn + ni * 16 + ln];

#pragma unroll
    for (int mi = 0; mi < 4; mi++) {
#pragma unroll
        for (int r = 0; r < 4; r++) {
            int row = wm + mi * 16 + q * 4 + r;   // C/D layout: row = quad*4 + reg
            if (row < mvalid) {
                int t = tok[row];
                float sc = scl[row];
                size_t ob = (size_t)t * HID + n0 + wn + ln;
#pragma unroll
                for (int ni = 0; ni < 4; ni++)
                    out[ob + ni * 16] = sc * (acc[mi][ni][r] + bn[ni]);
            }
        }
    }
}

extern "C" void kernel_launch(void* const* d_in, const int* in_sizes, int n_in,
                              void* d_out, int out_size, void* d_ws, size_t ws_size,
                              hipStream_t stream) {
    const float* X    = (const float*)d_in[0];   // [8192,1024]
    const float* G    = (const float*)d_in[1];   // [8192,8]
    const float* W    = (const float*)d_in[2];   // [8,1024,1024]
    const float* Bias = (const float*)d_in[3];   // [8,1024]
    float* out = (float*)d_out;

    float* scale = (float*)d_ws;                              // 8192 f32 = 32 KB
    int* counts  = (int*)((char*)d_ws + 32768);               // 8 ints
    int* list    = (int*)((char*)d_ws + 36864);               // 8*8192 ints = 256 KB

    zero_counts_kernel<<<1, 64, 0, stream>>>(counts);
    route_kernel<<<TOK / 256, 256, 0, stream>>>(G, scale, counts, list);
    moe_gemm_kernel<<<NE * 64 * 8, 256, 0, stream>>>(X, W, Bias, scale, counts, list, out);
}

// Round 2
// 249.296 us; speedup vs baseline: 3.2559x; 3.2559x over previous
//
#include <hip/hip_runtime.h>
#include <hip/hip_bf16.h>
#include <cstdint>
#include <cstddef>

#define TOK 8192
#define HID 1024
#define NE 8

typedef __bf16 bf16x4 __attribute__((ext_vector_type(4)));
typedef __bf16 bf16x8 __attribute__((ext_vector_type(8)));
typedef float floatx4 __attribute__((ext_vector_type(4)));

static __device__ __forceinline__ __bf16 f2bf(float x) {
    unsigned u = __builtin_bit_cast(unsigned, x);
    u += 0x7fffu + ((u >> 16) & 1u);   // RNE (inputs finite)
    unsigned short hs = (unsigned short)(u >> 16);
    return __builtin_bit_cast(__bf16, hs);
}

__global__ void zero_counts_kernel(int* counts) {
    if (threadIdx.x < NE) counts[threadIdx.x] = 0;
}

__global__ void route_kernel(const float* __restrict__ gate, float* __restrict__ scale,
                             int* __restrict__ counts, int* __restrict__ list) {
    int t = blockIdx.x * blockDim.x + threadIdx.x;
    if (t >= TOK) return;
    float g[NE];
#pragma unroll
    for (int j = 0; j < NE; j++) g[j] = gate[t * NE + j];
    float gm = g[0]; int best = 0;
#pragma unroll
    for (int j = 1; j < NE; j++) {
        if (g[j] > gm) { gm = g[j]; best = j; }
    }
    float s = 0.f;
#pragma unroll
    for (int j = 0; j < NE; j++) s += __expf(g[j] - gm);
    scale[t] = 1.0f / s;
    int pos = atomicAdd(&counts[best], 1);
    list[best * TOK + pos] = t;
}

// X [T][H] fp32 -> Xb [T][H] bf16. One thread = 8 elements.
__global__ void cvt_x_kernel(const float* __restrict__ X, __bf16* __restrict__ Xb) {
    int idx = blockIdx.x * 256 + threadIdx.x;      // 1M threads
    const float4 a = *(const float4*)(X + (size_t)idx * 8);
    const float4 b = *(const float4*)(X + (size_t)idx * 8 + 4);
    bf16x8 v;
    v[0] = f2bf(a.x); v[1] = f2bf(a.y); v[2] = f2bf(a.z); v[3] = f2bf(a.w);
    v[4] = f2bf(b.x); v[5] = f2bf(b.y); v[6] = f2bf(b.z); v[7] = f2bf(b.w);
    *(bf16x8*)(Xb + (size_t)idx * 8) = v;
}

// W [E][K][N] fp32 -> Wt [E][N][K] bf16 via 64x64 LDS tiles.
__global__ void cvt_wt_kernel(const float* __restrict__ W, __bf16* __restrict__ Wt) {
    const int b = blockIdx.x;          // 8 * 256 blocks
    const int e = b >> 8;
    const int tk = (b >> 4) & 15;
    const int tn = b & 15;
    const int k0 = tk * 64, n0 = tn * 64;

    __shared__ float ld[64][65];
    const int t = threadIdx.x;
    {
        const int r4 = t >> 4, c4 = t & 15;
#pragma unroll
        for (int i = 0; i < 4; i++) {
            int kl = r4 + 16 * i;
            float4 v = *(const float4*)(W + ((size_t)e * HID + (k0 + kl)) * HID + n0 + c4 * 4);
            ld[kl][c4 * 4 + 0] = v.x; ld[kl][c4 * 4 + 1] = v.y;
            ld[kl][c4 * 4 + 2] = v.z; ld[kl][c4 * 4 + 3] = v.w;
        }
    }
    __syncthreads();
    {
        const int nl = t >> 2, kc2 = t & 3;
#pragma unroll
        for (int h = 0; h < 2; h++) {
            int c = kc2 + 4 * h;
            bf16x8 v;
#pragma unroll
            for (int j = 0; j < 8; j++) v[j] = f2bf(ld[c * 8 + j][nl]);
            *(bf16x8*)(Wt + ((size_t)e * HID + n0 + nl) * HID + k0 + c * 8) = v;
        }
    }
}

// Grouped GEMM, m97-structure: global_load_lds staging (A gathered via token list,
// B from pre-transposed Wt), unswizzled LDS [row][64], 128x128x64 tiles, 4 waves,
// 4x4 fragments of mfma_f32_16x16x32_bf16.
__launch_bounds__(256)
__global__ void moe_gemm_bf16(const __bf16* __restrict__ Xb, const __bf16* __restrict__ Wt,
                              const float* __restrict__ Bias, const float* __restrict__ scale,
                              const int* __restrict__ counts, const int* __restrict__ list,
                              float* __restrict__ out) {
    const int bid = blockIdx.x;
    const int e  = bid >> 9;
    const int nt = (bid >> 6) & 7;
    const int mt = bid & 63;

    const int cnt = counts[e];
    if (mt * 128 >= cnt) return;
    const int mvalid = min(128, cnt - mt * 128);
    const int n0 = nt * 128;

    __shared__ __bf16 As[128 * 64];
    __shared__ __bf16 Bs[128 * 64];
    __shared__ int   tok[128];
    __shared__ float scl[128];

    const int tid  = threadIdx.x;
    const int lane = tid & 63;
    const int wave = tid >> 6;

    if (tid < 128) {
        int g = mt * 128 + tid;
        int tk = (g < cnt) ? list[e * TOK + g] : 0;
        tok[tid] = tk;
        scl[tid] = (g < cnt) ? scale[tk] : 0.f;
    }
    __syncthreads();

    // Staging: wave w, step i covers LDS rows w*32+i*8 .. +8 (1 KB contiguous).
    // Lane -> (sub-row = lane>>3, chunk = lane&7); LDS slot = base + lane*16.
    const int srow = lane >> 3;
    const int kchunk = (lane & 7) * 8;      // element offset within row
    const __bf16* aptr[4];
    const __bf16* bptr[4];
#pragma unroll
    for (int i = 0; i < 4; i++) {
        int r = wave * 32 + i * 8 + srow;
        aptr[i] = Xb + (size_t)tok[r] * HID + kchunk;
        bptr[i] = Wt + ((size_t)e * HID + n0 + r) * HID + kchunk;
    }

    const int ln = lane & 15;
    const int q  = lane >> 4;
    const int wm = (wave >> 1) * 64;
    const int wn = (wave & 1) * 64;

    floatx4 acc[4][4];
#pragma unroll
    for (int mi = 0; mi < 4; mi++)
#pragma unroll
        for (int ni = 0; ni < 4; ni++) acc[mi][ni] = (floatx4){0.f, 0.f, 0.f, 0.f};

    for (int k0 = 0; k0 < HID; k0 += 64) {
#pragma unroll
        for (int i = 0; i < 4; i++) {
            __builtin_amdgcn_global_load_lds(
                (const __attribute__((address_space(1))) void*)(aptr[i] + k0),
                (__attribute__((address_space(3))) void*)(&As[(wave * 32 + i * 8) * 64]),
                16, 0, 0);
            __builtin_amdgcn_global_load_lds(
                (const __attribute__((address_space(1))) void*)(bptr[i] + k0),
                (__attribute__((address_space(3))) void*)(&Bs[(wave * 32 + i * 8) * 64]),
                16, 0, 0);
        }
        __syncthreads();

#pragma unroll
        for (int kk = 0; kk < 64; kk += 32) {
            bf16x8 af[4], bfv[4];
#pragma unroll
            for (int mi = 0; mi < 4; mi++)
                af[mi] = *(const bf16x8*)(&As[(wm + mi * 16 + ln) * 64 + kk + q * 8]);
#pragma unroll
            for (int ni = 0; ni < 4; ni++)
                bfv[ni] = *(const bf16x8*)(&Bs[(wn + ni * 16 + ln) * 64 + kk + q * 8]);
#pragma unroll
            for (int mi = 0; mi < 4; mi++)
#pragma unroll
                for (int ni = 0; ni < 4; ni++)
                    acc[mi][ni] = __builtin_amdgcn_mfma_f32_16x16x32_bf16(
                        af[mi], bfv[ni], acc[mi][ni], 0, 0, 0);
        }
        __syncthreads();
    }

    float bn[4];
#pragma unroll
    for (int ni = 0; ni < 4; ni++) bn[ni] = Bias[e * HID + n0 + wn + ni * 16 + ln];

#pragma unroll
    for (int mi = 0; mi < 4; mi++) {
#pragma unroll
        for (int r = 0; r < 4; r++) {
            int row = wm + mi * 16 + q * 4 + r;
            if (row < mvalid) {
                int t = tok[row];
                float sc = scl[row];
                size_t ob = (size_t)t * HID + n0 + wn + ln;
#pragma unroll
                for (int ni = 0; ni < 4; ni++)
                    out[ob + ni * 16] = sc * (acc[mi][ni][r] + bn[ni]);
            }
        }
    }
}

// ---------------- fallback (ws too small): direct fp32 reads, compile-time j ----------------
__launch_bounds__(256)
__global__ void moe_gemm_fb(const float* __restrict__ X, const float* __restrict__ W,
                            const float* __restrict__ Bias, const float* __restrict__ scale,
                            const int* __restrict__ counts, const int* __restrict__ list,
                            float* __restrict__ out) {
    const int bid = blockIdx.x;
    const int e  = bid >> 9;
    const int nt = (bid >> 6) & 7;
    const int mt = bid & 63;
    const int cnt = counts[e];
    if (mt * 128 >= cnt) return;
    const int mvalid = min(128, cnt - mt * 128);
    const int n0 = nt * 128;

    __shared__ __bf16 As[128 * 64];
    __shared__ __bf16 Bs[128 * 64];
    __shared__ int   tok[128];
    __shared__ float scl[128];

    const int tid = threadIdx.x;
    if (tid < 128) {
        int g = mt * 128 + tid;
        int tk = (g < cnt) ? list[e * TOK + g] : 0;
        tok[tid] = tk;
        scl[tid] = (g < cnt) ? scale[tk] : 0.f;
    }
    __syncthreads();

    const int c4 = tid & 15;
    const float* rp[8];
    bool rv[8];
#pragma unroll
    for (int i = 0; i < 8; i++) {
        int m = (tid >> 4) + 16 * i;
        rv[i] = (m < mvalid);
        rp[i] = X + (size_t)tok[m] * HID;
    }
    const int n4 = tid & 31;
    const int kb = tid >> 5;
    const float* wbase = W + (size_t)e * HID * HID + (size_t)(kb * 8) * HID + n0 + n4 * 4;

    const int lane = tid & 63;
    const int ln = lane & 15;
    const int q  = lane >> 4;
    const int wave = tid >> 6;
    const int wm = (wave >> 1) * 64;
    const int wn = (wave & 1) * 64;

    floatx4 acc[4][4];
#pragma unroll
    for (int mi = 0; mi < 4; mi++)
#pragma unroll
        for (int ni = 0; ni < 4; ni++) acc[mi][ni] = (floatx4){0.f, 0.f, 0.f, 0.f};

    for (int k0 = 0; k0 < HID; k0 += 64) {
#pragma unroll
        for (int i = 0; i < 8; i++) {
            int m = (tid >> 4) + 16 * i;
            float4 v = make_float4(0.f, 0.f, 0.f, 0.f);
            if (rv[i]) v = *(const float4*)(rp[i] + k0 + c4 * 4);
            bf16x4 b4;
            b4[0] = f2bf(v.x); b4[1] = f2bf(v.y); b4[2] = f2bf(v.z); b4[3] = f2bf(v.w);
            int chunk = c4 >> 1;
            int addr = m * 64 + ((chunk ^ (m & 7)) * 8) + (c4 & 1) * 4;
            *(bf16x4*)(&As[addr]) = b4;
        }
        {
            const float* wp = wbase + (size_t)k0 * HID;
            float4 rr[8];
#pragma unroll
            for (int r = 0; r < 8; r++) rr[r] = *(const float4*)(wp + (size_t)r * HID);
#pragma unroll
            for (int j = 0; j < 4; j++) {           // compile-time j: no dynamic reg indexing
                int n = n4 * 4 + j;
                int c = kb ^ (n & 7);
                bf16x8 pk;
                pk[0] = f2bf(j == 0 ? rr[0].x : j == 1 ? rr[0].y : j == 2 ? rr[0].z : rr[0].w);
                pk[1] = f2bf(j == 0 ? rr[1].x : j == 1 ? rr[1].y : j == 2 ? rr[1].z : rr[1].w);
                pk[2] = f2bf(j == 0 ? rr[2].x : j == 1 ? rr[2].y : j == 2 ? rr[2].z : rr[2].w);
                pk[3] = f2bf(j == 0 ? rr[3].x : j == 1 ? rr[3].y : j == 2 ? rr[3].z : rr[3].w);
                pk[4] = f2bf(j == 0 ? rr[4].x : j == 1 ? rr[4].y : j == 2 ? rr[4].z : rr[4].w);
                pk[5] = f2bf(j == 0 ? rr[5].x : j == 1 ? rr[5].y : j == 2 ? rr[5].z : rr[5].w);
                pk[6] = f2bf(j == 0 ? rr[6].x : j == 1 ? rr[6].y : j == 2 ? rr[6].z : rr[6].w);
                pk[7] = f2bf(j == 0 ? rr[7].x : j == 1 ? rr[7].y : j == 2 ? rr[7].z : rr[7].w);
                *(bf16x8*)(&Bs[n * 64 + c * 8]) = pk;
            }
        }
        __syncthreads();
#pragma unroll
        for (int kk = 0; kk < 64; kk += 32) {
            const int cbase = (kk >> 3) + q;
            bf16x8 af[4], bfv[4];
#pragma unroll
            for (int mi = 0; mi < 4; mi++) {
                int row = wm + mi * 16 + ln;
                af[mi] = *(const bf16x8*)(&As[row * 64 + ((cbase ^ (row & 7)) * 8)]);
            }
#pragma unroll
            for (int ni = 0; ni < 4; ni++) {
                int n = wn + ni * 16 + ln;
                bfv[ni] = *(const bf16x8*)(&Bs[n * 64 + ((cbase ^ (n & 7)) * 8)]);
            }
#pragma unroll
            for (int mi = 0; mi < 4; mi++)
#pragma unroll
                for (int ni = 0; ni < 4; ni++)
                    acc[mi][ni] = __builtin_amdgcn_mfma_f32_16x16x32_bf16(
                        af[mi], bfv[ni], acc[mi][ni], 0, 0, 0);
        }
        __syncthreads();
    }

    float bn[4];
#pragma unroll
    for (int ni = 0; ni < 4; ni++) bn[ni] = Bias[e * HID + n0 + wn + ni * 16 + ln];
#pragma unroll
    for (int mi = 0; mi < 4; mi++) {
#pragma unroll
        for (int r = 0; r < 4; r++) {
            int row = wm + mi * 16 + q * 4 + r;
            if (row < mvalid) {
                int t = tok[row];
                float sc = scl[row];
                size_t ob = (size_t)t * HID + n0 + wn + ln;
#pragma unroll
                for (int ni = 0; ni < 4; ni++)
                    out[ob + ni * 16] = sc * (acc[mi][ni][r] + bn[ni]);
            }
        }
    }
}

extern "C" void kernel_launch(void* const* d_in, const int* in_sizes, int n_in,
                              void* d_out, int out_size, void* d_ws, size_t ws_size,
                              hipStream_t stream) {
    const float* X    = (const float*)d_in[0];
    const float* G    = (const float*)d_in[1];
    const float* W    = (const float*)d_in[2];
    const float* Bias = (const float*)d_in[3];
    float* out = (float*)d_out;

    float* scale = (float*)d_ws;                               // 32 KB
    int* counts  = (int*)((char*)d_ws + 32768);                // +4 KB pad
    int* list    = (int*)((char*)d_ws + 36864);                // 256 KB -> ends 299008
    __bf16* Xb   = (__bf16*)((char*)d_ws + 299008);            // 16 MB
    __bf16* Wt   = (__bf16*)((char*)d_ws + 299008 + 16777216); // 16 MB
    const size_t need = 299008 + 2 * 16777216ULL;

    zero_counts_kernel<<<1, 64, 0, stream>>>(counts);
    route_kernel<<<TOK / 256, 256, 0, stream>>>(G, scale, counts, list);

    if (ws_size >= need) {
        cvt_x_kernel<<<TOK * HID / (8 * 256), 256, 0, stream>>>(X, Xb);
        cvt_wt_kernel<<<NE * 256, 256, 0, stream>>>(W, Wt);
        moe_gemm_bf16<<<NE * 64 * 8, 256, 0, stream>>>(Xb, Wt, Bias, scale, counts, list, out);
    } else {
        moe_gemm_fb<<<NE * 64 * 8, 256, 0, stream>>>(X, W, Bias, scale, counts, list, out);
    }
}

// Round 3
// 150.417 us; speedup vs baseline: 5.3963x; 1.6574x over previous
//
#include <hip/hip_runtime.h>
#include <hip/hip_bf16.h>
#include <cstdint>
#include <cstddef>

#define TOK 8192
#define HID 1024
#define NE 8

typedef __bf16 bf16x4 __attribute__((ext_vector_type(4)));
typedef __bf16 bf16x8 __attribute__((ext_vector_type(8)));
typedef float floatx4 __attribute__((ext_vector_type(4)));

static __device__ __forceinline__ __bf16 f2bf(float x) {
    unsigned u = __builtin_bit_cast(unsigned, x);
    u += 0x7fffu + ((u >> 16) & 1u);   // RNE (inputs finite)
    unsigned short hs = (unsigned short)(u >> 16);
    return __builtin_bit_cast(__bf16, hs);
}

// Fused prep:
//   blocks [0, 4096):    X fp32 -> Xb bf16 (8 elems/thread); blocks [0,32) also route.
//   blocks [4096, 6144): W [E][K][N] fp32 -> Wt [E][N][K] bf16, 64x64 LDS transpose tiles.
__global__ void prep_kernel(const float* __restrict__ X, const float* __restrict__ gate,
                            const float* __restrict__ W,
                            __bf16* __restrict__ Xb, __bf16* __restrict__ Wt,
                            float* __restrict__ scale, int* __restrict__ counts,
                            int* __restrict__ list) {
    const int b = blockIdx.x;
    const int t = threadIdx.x;

    if (b < 4096) {
        // ---- cvt_x ----
        size_t idx = (size_t)b * 256 + t;
        const float4 a0 = *(const float4*)(X + idx * 8);
        const float4 a1 = *(const float4*)(X + idx * 8 + 4);
        bf16x8 v;
        v[0] = f2bf(a0.x); v[1] = f2bf(a0.y); v[2] = f2bf(a0.z); v[3] = f2bf(a0.w);
        v[4] = f2bf(a1.x); v[5] = f2bf(a1.y); v[6] = f2bf(a1.z); v[7] = f2bf(a1.w);
        *(bf16x8*)(Xb + idx * 8) = v;

        // ---- route (blocks 0..31, one token per thread, LDS histogram) ----
        if (b < 32) {
            __shared__ int hcnt[NE];
            __shared__ int hbase[NE];
            if (t < NE) hcnt[t] = 0;
            __syncthreads();
            int tok = b * 256 + t;
            float g[NE];
#pragma unroll
            for (int j = 0; j < NE; j++) g[j] = gate[tok * NE + j];
            float gm = g[0]; int best = 0;
#pragma unroll
            for (int j = 1; j < NE; j++) {
                if (g[j] > gm) { gm = g[j]; best = j; }   // strict >: first-max (argmax)
            }
            float s = 0.f;
#pragma unroll
            for (int j = 0; j < NE; j++) s += __expf(g[j] - gm);
            scale[tok] = 1.0f / s;
            int lpos = atomicAdd(&hcnt[best], 1);
            __syncthreads();
            if (t < NE) hbase[t] = atomicAdd(&counts[t], hcnt[t]);
            __syncthreads();
            list[best * TOK + hbase[best] + lpos] = tok;
        }
    } else {
        // ---- cvt_wt ----
        const int bb = b - 4096;
        const int e = bb >> 8;
        const int tk = (bb >> 4) & 15;
        const int tn = bb & 15;
        const int k0 = tk * 64, n0 = tn * 64;

        __shared__ float ld[64][65];
        {
            const int r4 = t >> 4, c4 = t & 15;
#pragma unroll
            for (int i = 0; i < 4; i++) {
                int kl = r4 + 16 * i;
                float4 v = *(const float4*)(W + ((size_t)e * HID + (k0 + kl)) * HID + n0 + c4 * 4);
                ld[kl][c4 * 4 + 0] = v.x; ld[kl][c4 * 4 + 1] = v.y;
                ld[kl][c4 * 4 + 2] = v.z; ld[kl][c4 * 4 + 3] = v.w;
            }
        }
        __syncthreads();
        {
            const int nl = t >> 2, kc2 = t & 3;
#pragma unroll
            for (int h = 0; h < 2; h++) {
                int c = kc2 + 4 * h;
                bf16x8 v;
#pragma unroll
                for (int j = 0; j < 8; j++) v[j] = f2bf(ld[c * 8 + j][nl]);
                *(bf16x8*)(Wt + ((size_t)e * HID + n0 + nl) * HID + k0 + c * 8) = v;
            }
        }
    }
}

// Grouped GEMM, m97-structure + two swizzles:
//  * XCD swizzle: bid = (e*64 + mt)*8 + nt  -> all m-tiles sharing a Wt n-slice sit on
//    one XCD (XCD ~ bid%8), making B L2-resident (8 experts x 256KB = 2MB per XCD).
//  * LDS chunk swizzle: element-chunk c of row r lives at position c^(r&7); row stride
//    is 64 bf16 (=32 banks), so the XOR spreads quad reads across all 8 bank groups.
//    Staging picks the global chunk (p ^ srow) so the wave-uniform global_load_lds
//    destination (base + lane*16) lands each chunk in its swizzled slot.
__launch_bounds__(256)
__global__ void moe_gemm_bf16(const __bf16* __restrict__ Xb, const __bf16* __restrict__ Wt,
                              const float* __restrict__ Bias, const float* __restrict__ scale,
                              const int* __restrict__ counts, const int* __restrict__ list,
                              float* __restrict__ out) {
    const int bid = blockIdx.x;
    const int nt = bid & 7;
    const int mt = (bid >> 3) & 63;
    const int e  = bid >> 9;

    const int cnt = counts[e];
    if (mt * 128 >= cnt) return;
    const int mvalid = min(128, cnt - mt * 128);
    const int n0 = nt * 128;

    __shared__ __bf16 As[128 * 64];
    __shared__ __bf16 Bs[128 * 64];
    __shared__ int   tok[128];
    __shared__ float scl[128];

    const int tid  = threadIdx.x;
    const int lane = tid & 63;
    const int wave = tid >> 6;

    if (tid < 128) {
        int g = mt * 128 + tid;
        int tk = (g < cnt) ? list[e * TOK + g] : 0;
        tok[tid] = tk;
        scl[tid] = (g < cnt) ? scale[tk] : 0.f;
    }
    __syncthreads();

    // Staging: wave w, step i covers LDS rows w*32+i*8 .. +8 (1 KB contiguous).
    // lane -> srow = lane>>3 (row within step), p = lane&7 (LDS chunk slot).
    // Global chunk fetched = p ^ srow, so LDS slot p holds chunk (p ^ row&7).
    const int srow = lane >> 3;
    const int gchunk = ((lane & 7) ^ srow) * 8;   // element offset within row
    const __bf16* aptr[4];
    const __bf16* bptr[4];
#pragma unroll
    for (int i = 0; i < 4; i++) {
        int r = wave * 32 + i * 8 + srow;
        aptr[i] = Xb + (size_t)tok[r] * HID + gchunk;
        bptr[i] = Wt + ((size_t)e * HID + n0 + r) * HID + gchunk;
    }

    const int ln = lane & 15;
    const int q  = lane >> 4;
    const int wm = (wave >> 1) * 64;
    const int wn = (wave & 1) * 64;
    const int rsw = ln & 7;                // row&7 for all fragment rows this lane reads

    floatx4 acc[4][4];
#pragma unroll
    for (int mi = 0; mi < 4; mi++)
#pragma unroll
        for (int ni = 0; ni < 4; ni++) acc[mi][ni] = (floatx4){0.f, 0.f, 0.f, 0.f};

    for (int k0 = 0; k0 < HID; k0 += 64) {
#pragma unroll
        for (int i = 0; i < 4; i++) {
            __builtin_amdgcn_global_load_lds(
                (const __attribute__((address_space(1))) void*)(aptr[i] + k0),
                (__attribute__((address_space(3))) void*)(&As[(wave * 32 + i * 8) * 64]),
                16, 0, 0);
            __builtin_amdgcn_global_load_lds(
                (const __attribute__((address_space(1))) void*)(bptr[i] + k0),
                (__attribute__((address_space(3))) void*)(&Bs[(wave * 32 + i * 8) * 64]),
                16, 0, 0);
        }
        __syncthreads();

#pragma unroll
        for (int kk = 0; kk < 64; kk += 32) {
            const int cb = (kk >> 3) + q;          // element chunk 0..7
            const int pos = (cb ^ rsw) * 8;        // swizzled slot
            bf16x8 af[4], bfv[4];
#pragma unroll
            for (int mi = 0; mi < 4; mi++)
                af[mi] = *(const bf16x8*)(&As[(wm + mi * 16 + ln) * 64 + pos]);
#pragma unroll
            for (int ni = 0; ni < 4; ni++)
                bfv[ni] = *(const bf16x8*)(&Bs[(wn + ni * 16 + ln) * 64 + pos]);
#pragma unroll
            for (int mi = 0; mi < 4; mi++)
#pragma unroll
                for (int ni = 0; ni < 4; ni++)
                    acc[mi][ni] = __builtin_amdgcn_mfma_f32_16x16x32_bf16(
                        af[mi], bfv[ni], acc[mi][ni], 0, 0, 0);
        }
        __syncthreads();
    }

    float bn[4];
#pragma unroll
    for (int ni = 0; ni < 4; ni++) bn[ni] = Bias[e * HID + n0 + wn + ni * 16 + ln];

#pragma unroll
    for (int mi = 0; mi < 4; mi++) {
#pragma unroll
        for (int r = 0; r < 4; r++) {
            int row = wm + mi * 16 + q * 4 + r;
            if (row < mvalid) {
                int t = tok[row];
                float sc = scl[row];
                size_t ob = (size_t)t * HID + n0 + wn + ln;
#pragma unroll
                for (int ni = 0; ni < 4; ni++)
                    out[ob + ni * 16] = sc * (acc[mi][ni][r] + bn[ni]);
            }
        }
    }
}

// ---------------- fallback (ws too small): direct fp32 reads, compile-time j ----------------
__launch_bounds__(256)
__global__ void moe_gemm_fb(const float* __restrict__ X, const float* __restrict__ W,
                            const float* __restrict__ Bias, const float* __restrict__ scale,
                            const int* __restrict__ counts, const int* __restrict__ list,
                            float* __restrict__ out) {
    const int bid = blockIdx.x;
    const int e  = bid >> 9;
    const int nt = (bid >> 6) & 7;
    const int mt = bid & 63;
    const int cnt = counts[e];
    if (mt * 128 >= cnt) return;
    const int mvalid = min(128, cnt - mt * 128);
    const int n0 = nt * 128;

    __shared__ __bf16 As[128 * 64];
    __shared__ __bf16 Bs[128 * 64];
    __shared__ int   tok[128];
    __shared__ float scl[128];

    const int tid = threadIdx.x;
    if (tid < 128) {
        int g = mt * 128 + tid;
        int tk = (g < cnt) ? list[e * TOK + g] : 0;
        tok[tid] = tk;
        scl[tid] = (g < cnt) ? scale[tk] : 0.f;
    }
    __syncthreads();

    const int c4 = tid & 15;
    const float* rp[8];
    bool rv[8];
#pragma unroll
    for (int i = 0; i < 8; i++) {
        int m = (tid >> 4) + 16 * i;
        rv[i] = (m < mvalid);
        rp[i] = X + (size_t)tok[m] * HID;
    }
    const int n4 = tid & 31;
    const int kb = tid >> 5;
    const float* wbase = W + (size_t)e * HID * HID + (size_t)(kb * 8) * HID + n0 + n4 * 4;

    const int lane = tid & 63;
    const int ln = lane & 15;
    const int q  = lane >> 4;
    const int wave = tid >> 6;
    const int wm = (wave >> 1) * 64;
    const int wn = (wave & 1) * 64;

    floatx4 acc[4][4];
#pragma unroll
    for (int mi = 0; mi < 4; mi++)
#pragma unroll
        for (int ni = 0; ni < 4; ni++) acc[mi][ni] = (floatx4){0.f, 0.f, 0.f, 0.f};

    for (int k0 = 0; k0 < HID; k0 += 64) {
#pragma unroll
        for (int i = 0; i < 8; i++) {
            int m = (tid >> 4) + 16 * i;
            float4 v = make_float4(0.f, 0.f, 0.f, 0.f);
            if (rv[i]) v = *(const float4*)(rp[i] + k0 + c4 * 4);
            bf16x4 b4;
            b4[0] = f2bf(v.x); b4[1] = f2bf(v.y); b4[2] = f2bf(v.z); b4[3] = f2bf(v.w);
            int chunk = c4 >> 1;
            int addr = m * 64 + ((chunk ^ (m & 7)) * 8) + (c4 & 1) * 4;
            *(bf16x4*)(&As[addr]) = b4;
        }
        {
            const float* wp = wbase + (size_t)k0 * HID;
            float4 rr[8];
#pragma unroll
            for (int r = 0; r < 8; r++) rr[r] = *(const float4*)(wp + (size_t)r * HID);
#pragma unroll
            for (int j = 0; j < 4; j++) {
                int n = n4 * 4 + j;
                int c = kb ^ (n & 7);
                bf16x8 pk;
                pk[0] = f2bf(j == 0 ? rr[0].x : j == 1 ? rr[0].y : j == 2 ? rr[0].z : rr[0].w);
                pk[1] = f2bf(j == 0 ? rr[1].x : j == 1 ? rr[1].y : j == 2 ? rr[1].z : rr[1].w);
                pk[2] = f2bf(j == 0 ? rr[2].x : j == 1 ? rr[2].y : j == 2 ? rr[2].z : rr[2].w);
                pk[3] = f2bf(j == 0 ? rr[3].x : j == 1 ? rr[3].y : j == 2 ? rr[3].z : rr[3].w);
                pk[4] = f2bf(j == 0 ? rr[4].x : j == 1 ? rr[4].y : j == 2 ? rr[4].z : rr[4].w);
                pk[5] = f2bf(j == 0 ? rr[5].x : j == 1 ? rr[5].y : j == 2 ? rr[5].z : rr[5].w);
                pk[6] = f2bf(j == 0 ? rr[6].x : j == 1 ? rr[6].y : j == 2 ? rr[6].z : rr[6].w);
                pk[7] = f2bf(j == 0 ? rr[7].x : j == 1 ? rr[7].y : j == 2 ? rr[7].z : rr[7].w);
                *(bf16x8*)(&Bs[n * 64 + c * 8]) = pk;
            }
        }
        __syncthreads();
#pragma unroll
        for (int kk = 0; kk < 64; kk += 32) {
            const int cbase = (kk >> 3) + q;
            bf16x8 af[4], bfv[4];
#pragma unroll
            for (int mi = 0; mi < 4; mi++) {
                int row = wm + mi * 16 + ln;
                af[mi] = *(const bf16x8*)(&As[row * 64 + ((cbase ^ (row & 7)) * 8)]);
            }
#pragma unroll
            for (int ni = 0; ni < 4; ni++) {
                int n = wn + ni * 16 + ln;
                bfv[ni] = *(const bf16x8*)(&Bs[n * 64 + ((cbase ^ (n & 7)) * 8)]);
            }
#pragma unroll
            for (int mi = 0; mi < 4; mi++)
#pragma unroll
                for (int ni = 0; ni < 4; ni++)
                    acc[mi][ni] = __builtin_amdgcn_mfma_f32_16x16x32_bf16(
                        af[mi], bfv[ni], acc[mi][ni], 0, 0, 0);
        }
        __syncthreads();
    }

    float bn[4];
#pragma unroll
    for (int ni = 0; ni < 4; ni++) bn[ni] = Bias[e * HID + n0 + wn + ni * 16 + ln];
#pragma unroll
    for (int mi = 0; mi < 4; mi++) {
#pragma unroll
        for (int r = 0; r < 4; r++) {
            int row = wm + mi * 16 + q * 4 + r;
            if (row < mvalid) {
                int t = tok[row];
                float sc = scl[row];
                size_t ob = (size_t)t * HID + n0 + wn + ln;
#pragma unroll
                for (int ni = 0; ni < 4; ni++)
                    out[ob + ni * 16] = sc * (acc[mi][ni][r] + bn[ni]);
            }
        }
    }
}

__global__ void zero_counts_kernel(int* counts) {
    if (threadIdx.x < NE) counts[threadIdx.x] = 0;
}

__global__ void route_fb_kernel(const float* __restrict__ gate, float* __restrict__ scale,
                                int* __restrict__ counts, int* __restrict__ list) {
    int t = blockIdx.x * blockDim.x + threadIdx.x;
    if (t >= TOK) return;
    float g[NE];
#pragma unroll
    for (int j = 0; j < NE; j++) g[j] = gate[t * NE + j];
    float gm = g[0]; int best = 0;
#pragma unroll
    for (int j = 1; j < NE; j++) {
        if (g[j] > gm) { gm = g[j]; best = j; }
    }
    float s = 0.f;
#pragma unroll
    for (int j = 0; j < NE; j++) s += __expf(g[j] - gm);
    scale[t] = 1.0f / s;
    int pos = atomicAdd(&counts[best], 1);
    list[best * TOK + pos] = t;
}

extern "C" void kernel_launch(void* const* d_in, const int* in_sizes, int n_in,
                              void* d_out, int out_size, void* d_ws, size_t ws_size,
                              hipStream_t stream) {
    const float* X    = (const float*)d_in[0];
    const float* G    = (const float*)d_in[1];
    const float* W    = (const float*)d_in[2];
    const float* Bias = (const float*)d_in[3];
    float* out = (float*)d_out;

    float* scale = (float*)d_ws;                               // 32 KB
    int* counts  = (int*)((char*)d_ws + 32768);                // 32 B (+pad)
    int* list    = (int*)((char*)d_ws + 36864);                // 256 KB -> ends 299008
    __bf16* Xb   = (__bf16*)((char*)d_ws + 299008);            // 16 MB
    __bf16* Wt   = (__bf16*)((char*)d_ws + 299008 + 16777216); // 16 MB
    const size_t need = 299008 + 2 * 16777216ULL;

    hipMemsetAsync(counts, 0, NE * sizeof(int), stream);

    if (ws_size >= need) {
        prep_kernel<<<6144, 256, 0, stream>>>(X, G, W, Xb, Wt, scale, counts, list);
        moe_gemm_bf16<<<NE * 64 * 8, 256, 0, stream>>>(Xb, Wt, Bias, scale, counts, list, out);
    } else {
        route_fb_kernel<<<TOK / 256, 256, 0, stream>>>(G, scale, counts, list);
        moe_gemm_fb<<<NE * 64 * 8, 256, 0, stream>>>(X, W, Bias, scale, counts, list, out);
    }
}